// Round 1
// 3046.556 us; speedup vs baseline: 2.5418x; 2.5418x over previous
//
#include <hip/hip_runtime.h>
#include <hip/hip_bf16.h>

#define N_DIM 16384
#define CN (256L * 16384)

using bf16 = __hip_bfloat16;

typedef __attribute__((ext_vector_type(8))) short short8;
typedef __attribute__((ext_vector_type(4))) float f32x4;
typedef __attribute__((ext_vector_type(4))) unsigned int u32x4;

// ---------- small helpers ----------

__device__ __forceinline__ unsigned short f2bf(float x) {   // RNE float->bf16 (finite inputs)
    unsigned int u = __float_as_uint(x);
    u = (u + 0x7FFFu + ((u >> 16) & 1u)) >> 16;
    return (unsigned short)u;
}
__device__ __forceinline__ float bfus2f(unsigned short h) {
    return __uint_as_float(((unsigned int)h) << 16);
}

// MFMA via inline asm (gfx950 unified VGPR/AGPR file; D==C accumulate)
__device__ __forceinline__ void mfma16(f32x4& d, short8 a, short8 b) {
    asm("v_mfma_f32_16x16x32_bf16 %0, %1, %2, %0" : "+v"(d) : "v"(a), "v"(b));
}

// runtime-dtype load: isbf ? bf16 : fp32
__device__ inline float ldmix(const void* p, long i, int isbf) {
    return isbf ? __bfloat162float(((const bf16*)p)[i])
                : ((const float*)p)[i];
}

__device__ inline void st_out(float* p, long i, float v)  { p[i] = v; }
__device__ inline void st_out(bf16* p, long i, float v)   { p[i] = __float2bfloat16(v); }

__device__ inline float gelu_f(float x) {
    return 0.5f * x * (1.0f + erff(x * 0.70710678118654752440f));
}

__device__ inline float block_reduce_sum(float v, float* sh) {
    int t = threadIdx.x;
    sh[t] = v; __syncthreads();
    for (int s = 128; s >= 1; s >>= 1) {
        if (t < s) sh[t] += sh[t + s];
        __syncthreads();
    }
    float r = sh[0]; __syncthreads();
    return r;
}

__device__ inline float block_reduce_max(float v, float* sh) {
    int t = threadIdx.x;
    sh[t] = v; __syncthreads();
    for (int s = 128; s >= 1; s >>= 1) {
        if (t < s) sh[t] = fmaxf(sh[t], sh[t + s]);
        __syncthreads();
    }
    float r = sh[0]; __syncthreads();
    return r;
}

// write 16 bf16 elements to LDS from 2 (bf16 src) or 4 (fp32 src) u32x4 regs
__device__ __forceinline__ void wr16(short* d, const u32x4* r, int isbf) {
    if (isbf) {
        *(u32x4*)d = r[0]; *(u32x4*)(d + 8) = r[1];
    } else {
        #pragma unroll
        for (int g = 0; g < 2; ++g) {
            short8 h;
            #pragma unroll
            for (int i = 0; i < 8; ++i)
                h[i] = (short)f2bf(__uint_as_float(r[2*g + (i >> 2)][i & 3]));
            *(short8*)(d + g * 8) = h;
        }
    }
}

// ---------- dtype detection (unchanged) ----------

__global__ void detect_main(const unsigned short* __restrict__ p, int* __restrict__ flag) {
    __shared__ int cnt;
    int t = threadIdx.x;
    if (t == 0) cnt = 0;
    __syncthreads();
    int e = (p[t] >> 7) & 0xFF;
    if (e >= 90 && e <= 145) atomicAdd(&cnt, 1);
    __syncthreads();
    if (t == 0) *flag = (cnt >= 200) ? 1 : 0;
}

__global__ void detect_const(const unsigned short* __restrict__ p, int* __restrict__ flag) {
    __shared__ int zc;
    int t = threadIdx.x;
    if (t == 0) zc = 0;
    __syncthreads();
    if (p[t] == 0) atomicAdd(&zc, 1);
    __syncthreads();
    if (t == 0) *flag = (zc >= 64) ? 0 : 1;
}

__global__ void init_consts(int* flags) {
    flags[2] = 0;  // fp32 constant flag
    flags[3] = 1;  // bf16 constant flag
}

__global__ void cvt_small(const void* __restrict__ in, float* __restrict__ out,
                          int n, const int* __restrict__ flag) {
    int i = threadIdx.x;
    if (i < n) out[i] = ldmix(in, i, *flag);
}

// kvsum[j] = sum_n kv[j,n];  grid.x = 512
__global__ void rowsum_kv(const void* __restrict__ kv, float* __restrict__ kvsum,
                          const int* __restrict__ flag) {
    __shared__ float sh[256];
    int j = blockIdx.x, t = threadIdx.x, isbf = *flag;
    float s = 0.f;
    for (int n = t; n < N_DIM; n += 256) s += ldmix(kv, (long)j * N_DIM + n, isbf);
    s = block_reduce_sum(s, sh);
    if (t == 0) kvsum[j] = s;
}

// per-row stats of bf16 Z[256][N_DIM]: st[row]=(s, t, mean, 0), norm(x)=s*x+t
__global__ void row_stats(const bf16* __restrict__ Z,
                          const float* __restrict__ gamma,
                          const float* __restrict__ beta,
                          float4* __restrict__ st) {
    __shared__ float sh[256];
    int row = blockIdx.x, t = threadIdx.x;
    const bf16* z = Z + (long)row * N_DIM;
    float s = 0.f, s2 = 0.f;
    for (int i = t; i < N_DIM; i += 256) {
        float v = __bfloat162float(z[i]);
        s += v; s2 += v * v;
    }
    float sum  = block_reduce_sum(s, sh);
    float sum2 = block_reduce_sum(s2, sh);
    if (t == 0) {
        float mean = sum * (1.0f / N_DIM);
        float var  = fmaxf(sum2 * (1.0f / N_DIM) - mean * mean, 0.0f);
        float inv  = rsqrtf(var + 1e-5f);
        float sc = gamma[row] * inv;
        st[row] = make_float4(sc, beta[row] - mean * sc, mean, 0.0f);
    }
}

// in-place instance-norm + softmax over rows of length L (256 or 512); grid.x=256
__global__ void inorm_softmax(float* __restrict__ S, int L) {
    __shared__ float sh[256];
    float* row = S + (long)blockIdx.x * L;
    int t = threadIdx.x;
    float x0 = row[t];
    float x1 = (L > 256) ? row[t + 256] : 0.0f;
    float sum = block_reduce_sum(x0 + x1, sh);
    float mean = sum / (float)L;
    float d0 = x0 - mean;
    float d1 = (L > 256) ? (x1 - mean) : 0.0f;
    float var = fmaxf(block_reduce_sum(d0 * d0 + d1 * d1, sh) / (float)L, 0.0f);
    float inv = rsqrtf(var + 1e-5f);
    float y0 = d0 * inv, y1 = d1 * inv;
    float mx = (L > 256) ? fmaxf(y0, y1) : y0;
    float gmax = block_reduce_max(mx, sh);
    float e0 = expf(y0 - gmax);
    float e1 = (L > 256) ? expf(y1 - gmax) : 0.0f;
    float es = block_reduce_sum(e0 + e1, sh);
    float rinv = 1.0f / es;
    row[t] = e0 * rinv;
    if (L > 256) row[t + 256] = e1 * rinv;
}

// ---------------------------------------------------------------------------
// MFMA big NN GEMM: Cout[256][N_DIM] = A[256][K] @ B[K][N_DIM] (+rowc)(+Dres)(gelu)
// A is split hi/lo bf16 (fp32-accurate weights); B single bf16.
// tile 128x128, BK=32, 4 waves (2x2, 64x64 each), double-buffered LDS.
// grid (N_DIM/128, 2), block 256.
// ---------------------------------------------------------------------------
template <bool RES, bool GELU, typename TOUT>
__global__ __launch_bounds__(256, 1) void gemm_nn_mfma(
    const void* __restrict__ Ag, const int* __restrict__ fA,
    const void* __restrict__ Bg, const int* __restrict__ fB, long boff,
    const float* __restrict__ rowc, const bf16* __restrict__ Dres,
    TOUT* __restrict__ Cout, int K)
{
    __shared__ short Ahi[2][128 * 40];   // [row][k] pitch 40 (80B, 16B-aligned rows)
    __shared__ short Alo[2][128 * 40];
    __shared__ short Bsm[2][32 * 130];   // [k][n] pitch 130 (260B -> bank = k + n/2, conflict-free)

    int t = threadIdx.x;
    int af = *fA, bfg = *fB;
    int n0 = blockIdx.x * 128, m0 = blockIdx.y * 128;
    int wave = t >> 6, lane = t & 63;
    int wr = wave >> 1, wc = wave & 1;
    int l15 = lane & 15, lkg = lane >> 4;
    int arow = t & 127, ah2 = t >> 7;    // A staging: row, 16-k half

    u32x4 ra[4], rb[4];
    f32x4 acc[4][4];
    f32x4 zz = {0.f, 0.f, 0.f, 0.f};
    #pragma unroll
    for (int mi = 0; mi < 4; ++mi)
        #pragma unroll
        for (int ni = 0; ni < 4; ++ni) acc[mi][ni] = zz;

    auto STAGE_LOAD = [&](int k0) {
        long ga = (long)(m0 + arow) * K + k0 + ah2 * 16;
        if (af) {
            const u32x4* p = (const u32x4*)((const unsigned short*)Ag + ga);
            ra[0] = p[0]; ra[1] = p[1];
        } else {
            const u32x4* p = (const u32x4*)((const float*)Ag + ga);
            ra[0] = p[0]; ra[1] = p[1]; ra[2] = p[2]; ra[3] = p[3];
        }
        #pragma unroll
        for (int c = 0; c < 2; ++c) {
            int q = c * 256 + t;
            int k = q >> 4, n = (q & 15) * 8;
            long gb = boff + (long)(k0 + k) * N_DIM + n0 + n;
            if (bfg) {
                rb[c * 2] = *(const u32x4*)((const unsigned short*)Bg + gb);
            } else {
                const u32x4* p = (const u32x4*)((const float*)Bg + gb);
                rb[c * 2] = p[0]; rb[c * 2 + 1] = p[1];
            }
        }
    };

    auto STAGE_WRITE = [&](int b2) {
        short* dh = &Ahi[b2][arow * 40 + ah2 * 16];
        short* dl = &Alo[b2][arow * 40 + ah2 * 16];
        if (af) {
            *(u32x4*)dh = ra[0]; *(u32x4*)(dh + 8) = ra[1];
            u32x4 z4 = {0u, 0u, 0u, 0u};
            *(u32x4*)dl = z4; *(u32x4*)(dl + 8) = z4;
        } else {
            #pragma unroll
            for (int g = 0; g < 2; ++g) {
                short8 h, l;
                #pragma unroll
                for (int i = 0; i < 8; ++i) {
                    float x = __uint_as_float(ra[2 * g + (i >> 2)][i & 3]);
                    unsigned short hu = f2bf(x);
                    h[i] = (short)hu;
                    l[i] = (short)f2bf(x - bfus2f(hu));
                }
                *(short8*)(dh + g * 8) = h;
                *(short8*)(dl + g * 8) = l;
            }
        }
        #pragma unroll
        for (int c = 0; c < 2; ++c) {
            int q = c * 256 + t;
            int k = q >> 4, n = (q & 15) * 8;
            unsigned int* wp = (unsigned int*)&Bsm[b2][k * 130 + n];
            if (bfg) {
                const unsigned int* s = (const unsigned int*)&rb[c * 2];
                wp[0] = s[0]; wp[1] = s[1]; wp[2] = s[2]; wp[3] = s[3];
            } else {
                #pragma unroll
                for (int j = 0; j < 4; ++j) {
                    float x0 = __uint_as_float(rb[c * 2 + (j >> 1)][(j & 1) * 2]);
                    float x1 = __uint_as_float(rb[c * 2 + (j >> 1)][(j & 1) * 2 + 1]);
                    wp[j] = (unsigned int)f2bf(x0) | ((unsigned int)f2bf(x1) << 16);
                }
            }
        }
    };

    auto COMPUTE = [&](int b2) {
        const short* AhB = &Ahi[b2][0];
        const short* AlB = &Alo[b2][0];
        const short* BsB = &Bsm[b2][0];
        short8 bfr[4];
        #pragma unroll
        for (int ni = 0; ni < 4; ++ni) {
            short8 v;
            #pragma unroll
            for (int e = 0; e < 8; ++e)
                v[e] = BsB[(lkg * 8 + e) * 130 + wc * 64 + ni * 16 + l15];
            bfr[ni] = v;
        }
        short8 ahf[4], alf[4];
        #pragma unroll
        for (int mi = 0; mi < 4; ++mi) {
            int ro = (wr * 64 + mi * 16 + l15) * 40 + lkg * 8;
            ahf[mi] = *(const short8*)(AhB + ro);
            alf[mi] = *(const short8*)(AlB + ro);
        }
        // hi pass then lo pass (same-acc MFMAs kept 16 apart)
        #pragma unroll
        for (int mi = 0; mi < 4; ++mi)
            #pragma unroll
            for (int ni = 0; ni < 4; ++ni)
                mfma16(acc[mi][ni], ahf[mi], bfr[ni]);
        #pragma unroll
        for (int mi = 0; mi < 4; ++mi)
            #pragma unroll
            for (int ni = 0; ni < 4; ++ni)
                mfma16(acc[mi][ni], alf[mi], bfr[ni]);
    };

    int nsteps = K >> 5;
    STAGE_LOAD(0);
    STAGE_WRITE(0);
    __syncthreads();
    int buf = 0;
    for (int s = 0; s < nsteps; ++s) {
        bool pre = (s + 1 < nsteps);
        if (pre) STAGE_LOAD((s + 1) << 5);   // issue next-tile global loads early
        COMPUTE(buf);                        // MFMA on current buffer
        if (pre) STAGE_WRITE(buf ^ 1);       // write-late into other buffer
        __syncthreads();
        buf ^= 1;
    }

    // epilogue: D frag = col(lane&15), row (lane>>4)*4 + r   [measured m89/m91]
    #pragma unroll
    for (int mi = 0; mi < 4; ++mi) {
        #pragma unroll
        for (int ni = 0; ni < 4; ++ni) {
            int mbase = m0 + wr * 64 + mi * 16 + lkg * 4;
            int n = n0 + wc * 64 + ni * 16 + l15;
            #pragma unroll
            for (int r = 0; r < 4; ++r) {
                int m = mbase + r;
                float v = acc[mi][ni][r];
                if (rowc) v += rowc[m];
                if (RES)  v += __bfloat162float(Dres[(long)m * N_DIM + n]);
                if (GELU) v = gelu_f(v);
                st_out(Cout, (long)m * N_DIM + n, v);
            }
        }
    }
}

// ---------------------------------------------------------------------------
// MFMA big NT GEMM (split-K partials): Pout[z][256][J] = A[256][16384] @ B[J][16384]^T
// Both operands k-contiguous -> all frags ds_read_b128. tile 128x128, BK=32, dbuf.
// grid (J/128, 2, z), block 256.  kch = 16384 / z.
// ---------------------------------------------------------------------------
__global__ __launch_bounds__(256, 1) void gemm_nt_mfma(
    const void* __restrict__ Ag, const int* __restrict__ fA,
    const void* __restrict__ Bg, const int* __restrict__ fB,
    float* __restrict__ Pout, int J)
{
    __shared__ short Ash[2][128 * 40];
    __shared__ short Bs2[2][128 * 40];

    int t = threadIdx.x;
    int af = *fA, bfg = *fB;
    int j0 = blockIdx.x * 128, m0 = blockIdx.y * 128;
    int kch = N_DIM / gridDim.z;
    int kz = blockIdx.z * kch;
    int wave = t >> 6, lane = t & 63;
    int wr = wave >> 1, wc = wave & 1;
    int l15 = lane & 15, lkg = lane >> 4;
    int arow = t & 127, ah2 = t >> 7;

    u32x4 ra[4], rbn[4];
    f32x4 acc[4][4];
    f32x4 zz = {0.f, 0.f, 0.f, 0.f};
    #pragma unroll
    for (int mi = 0; mi < 4; ++mi)
        #pragma unroll
        for (int nj = 0; nj < 4; ++nj) acc[mi][nj] = zz;

    auto STAGE_LOAD = [&](int k0) {
        long ga = (long)(m0 + arow) * N_DIM + k0 + ah2 * 16;
        if (af) {
            const u32x4* p = (const u32x4*)((const unsigned short*)Ag + ga);
            ra[0] = p[0]; ra[1] = p[1];
        } else {
            const u32x4* p = (const u32x4*)((const float*)Ag + ga);
            ra[0] = p[0]; ra[1] = p[1]; ra[2] = p[2]; ra[3] = p[3];
        }
        long gb = (long)(j0 + arow) * N_DIM + k0 + ah2 * 16;
        if (bfg) {
            const u32x4* p = (const u32x4*)((const unsigned short*)Bg + gb);
            rbn[0] = p[0]; rbn[1] = p[1];
        } else {
            const u32x4* p = (const u32x4*)((const float*)Bg + gb);
            rbn[0] = p[0]; rbn[1] = p[1]; rbn[2] = p[2]; rbn[3] = p[3];
        }
    };

    auto STAGE_WRITE = [&](int b2) {
        wr16(&Ash[b2][arow * 40 + ah2 * 16], ra, af);
        wr16(&Bs2[b2][arow * 40 + ah2 * 16], rbn, bfg);
    };

    auto COMPUTE = [&](int b2) {
        const short* AsB = &Ash[b2][0];
        const short* BsB = &Bs2[b2][0];
        short8 a[4], b[4];
        #pragma unroll
        for (int mi = 0; mi < 4; ++mi)
            a[mi] = *(const short8*)(AsB + (wr * 64 + mi * 16 + l15) * 40 + lkg * 8);
        #pragma unroll
        for (int nj = 0; nj < 4; ++nj)
            b[nj] = *(const short8*)(BsB + (wc * 64 + nj * 16 + l15) * 40 + lkg * 8);
        #pragma unroll
        for (int mi = 0; mi < 4; ++mi)
            #pragma unroll
            for (int nj = 0; nj < 4; ++nj)
                mfma16(acc[mi][nj], a[mi], b[nj]);
    };

    int nsteps = kch >> 5;
    STAGE_LOAD(kz);
    STAGE_WRITE(0);
    __syncthreads();
    int buf = 0;
    for (int s = 0; s < nsteps; ++s) {
        bool pre = (s + 1 < nsteps);
        if (pre) STAGE_LOAD(kz + ((s + 1) << 5));
        COMPUTE(buf);
        if (pre) STAGE_WRITE(buf ^ 1);
        __syncthreads();
        buf ^= 1;
    }

    float* P = Pout + (long)blockIdx.z * 256 * J;
    #pragma unroll
    for (int mi = 0; mi < 4; ++mi) {
        #pragma unroll
        for (int nj = 0; nj < 4; ++nj) {
            int mbase = m0 + wr * 64 + mi * 16 + lkg * 4;
            int j = j0 + wc * 64 + nj * 16 + l15;
            #pragma unroll
            for (int r = 0; r < 4; ++r)
                P[(long)(mbase + r) * J + j] = acc[mi][nj][r];
        }
    }
}

// out[i] = sum_z part[z][i]; grid = ne/256
__global__ void red_nt(const float* __restrict__ part, float* __restrict__ out,
                       int ne, int z) {
    int i = blockIdx.x * 256 + threadIdx.x;
    float s = 0.f;
    for (int q = 0; q < z; ++q) s += part[(long)q * ne + i];
    out[i] = s;
}

// ---------------------------------------------------------------------------
// Small fp32 GEMM (unchanged this round): C[256][Nn] = alpha * A[256][K] @ op(B)
// ---------------------------------------------------------------------------
template <bool TRANSB>
__global__ __launch_bounds__(256) void gemm_small(
    const void* __restrict__ A, const int* __restrict__ fA, int K,
    const void* __restrict__ B, const int* __restrict__ fB, int ldb,
    float* __restrict__ C, int Nn, float alpha)
{
    __shared__ float As[64][65];
    __shared__ float Bs[64][65];
    int af = *fA, bfg = *fB;
    int j0 = blockIdx.x * 64, m0 = blockIdx.y * 64;
    int t = threadIdx.x, tx = t & 15, ty = t >> 4;
    float acc[4][4] = {{0.f}};

    for (int k0 = 0; k0 < K; k0 += 64) {
        #pragma unroll
        for (int i = 0; i < 16; ++i) {
            int idx = t + i * 256;
            int r = idx >> 6, c = idx & 63;
            As[c][r] = ldmix(A, (long)(m0 + r) * K + (k0 + c), af);
            if (TRANSB)
                Bs[c][r] = ldmix(B, (long)(j0 + r) * ldb + (k0 + c), bfg);
            else
                Bs[r][c] = ldmix(B, (long)(k0 + r) * ldb + (j0 + c), bfg);
        }
        __syncthreads();
        #pragma unroll
        for (int kk = 0; kk < 64; ++kk) {
            float a[4], bb[4];
            #pragma unroll
            for (int i = 0; i < 4; ++i) a[i] = As[kk][ty * 4 + i];
            #pragma unroll
            for (int j = 0; j < 4; ++j) bb[j] = Bs[kk][tx * 4 + j];
            #pragma unroll
            for (int i = 0; i < 4; ++i)
                #pragma unroll
                for (int j = 0; j < 4; ++j)
                    acc[i][j] = fmaf(a[i], bb[j], acc[i][j]);
        }
        __syncthreads();
    }

    #pragma unroll
    for (int i = 0; i < 4; ++i) {
        int m = m0 + ty * 4 + i;
        #pragma unroll
        for (int j = 0; j < 4; ++j)
            C[(long)m * Nn + (j0 + tx * 4 + j)] = acc[i][j] * alpha;
    }
}

// ---------- affine-stat fold kernels (unchanged) ----------

__global__ void build_G(const float* __restrict__ Gemb, const float4* __restrict__ st,
                        float* __restrict__ G) {
    int c = blockIdx.x, d = threadIdx.x;
    float4 a = st[c], b = st[d];
    float rc = a.z * (float)N_DIM, rd = b.z * (float)N_DIM;
    G[c * 256 + d] = a.x * b.x * Gemb[c * 256 + d]
                   + a.x * b.y * rc + a.y * b.x * rd
                   + (float)N_DIM * a.y * b.y;
}

__global__ void build_P(const float* __restrict__ Pemb, const float4* __restrict__ st,
                        const float* __restrict__ kvsum, float* __restrict__ P) {
    int c = blockIdx.x, t = threadIdx.x;
    float4 a = st[c];
    for (int j = t; j < 512; j += 256)
        P[c * 512 + j] = a.x * Pemb[c * 512 + j] + a.y * kvsum[j];
}

__global__ void build_Ms_u(const float* __restrict__ M, const float4* __restrict__ st,
                           float* __restrict__ Ms, float* __restrict__ u) {
    __shared__ float sh[256];
    int m = blockIdx.x, c = threadIdx.x;
    float mv = M[m * 256 + c];
    float4 b = st[c];
    Ms[m * 256 + c] = mv * b.x + ((m == c) ? 1.0f : 0.0f);
    float uu = block_reduce_sum(mv * b.y, sh);
    if (c == 0) u[m] = uu;
}

__global__ void build_W2_v(const void* __restrict__ Wout, const int* __restrict__ fM,
                           const float4* __restrict__ st,
                           float* __restrict__ W2, float* __restrict__ v) {
    __shared__ float sh[256];
    int o = blockIdx.x, c = threadIdx.x;
    float wv = ldmix(Wout, (long)o * 256 + c, *fM);
    float4 b = st[c];
    W2[o * 256 + c] = wv * b.x;
    float vv = block_reduce_sum(wv * b.y, sh);
    if (c == 0) v[o] = vv;
}

extern "C" void kernel_launch(void* const* d_in, const int* in_sizes, int n_in,
                              void* d_out, int out_size, void* d_ws, size_t ws_size,
                              hipStream_t stream) {
    const void* feats = d_in[0];
    const void* kv    = d_in[1];
    const void* W_in  = d_in[2];
    const void* W_out = d_in[3];
    const void* Wq_sa = d_in[4];
    const void* Wk_sa = d_in[5];
    const void* Wv_sa = d_in[6];
    const void* Wo_sa = d_in[7];
    const void* Wq_ca = d_in[8];
    const void* Wo_ca = d_in[9];
    float* OUT = (float*)d_out;   // reference output dtype is float32

    // ---- workspace (~37 MB) ----
    char* w = (char*)d_ws;
    auto alloc = [&](size_t bytes) { char* p = w; w += (bytes + 255) & ~255UL; return p; };
    int*    flags = (int*)alloc(64);
    float*  GA    = (float*)alloc(1024);
    float*  GAb   = (float*)alloc(1024);
    float*  EG    = (float*)alloc(1024);
    float*  EGb   = (float*)alloc(1024);
    float*  kvsum = (float*)alloc(2048);
    float4* ST1   = (float4*)alloc(4096);
    float4* ST2   = (float4*)alloc(4096);
    float*  Gemb  = (float*)alloc(262144);
    float*  Gf    = (float*)alloc(262144);
    float*  T1    = (float*)alloc(262144);
    float*  T2    = (float*)alloc(262144);
    float*  Mm    = (float*)alloc(262144);
    float*  Ms    = (float*)alloc(262144);
    float*  W2    = (float*)alloc(262144);
    float*  SC    = (float*)alloc(524288);
    float*  M2    = (float*)alloc(524288);
    float*  Pm    = (float*)alloc(524288);
    float*  Pemb  = (float*)alloc(524288);
    float*  uvec  = (float*)alloc(1024);
    float*  vvec  = (float*)alloc(1024);
    bf16*   EMB   = (bf16*)alloc(CN * 2);
    bf16*   SU    = (bf16*)alloc(CN * 2);
    // NT split-K partials reuse the (then-dead) SU region: max 8.4 MB, exact fit.
    float*  PART  = (float*)SU;

    const int* fM = flags + 0;  // detected dtype of main tensors
    const int* f0 = flags + 2;  // fp32 constant
    const int* f1 = flags + 3;  // bf16 constant

    // ---- setup ----
    detect_main<<<1, 256, 0, stream>>>((const unsigned short*)feats, flags + 0);
    detect_const<<<1, 256, 0, stream>>>((const unsigned short*)d_in[10], flags + 1);
    init_consts<<<1, 1, 0, stream>>>(flags);
    cvt_small<<<1, 256, 0, stream>>>(d_in[10], GA,  256, flags + 1);
    cvt_small<<<1, 256, 0, stream>>>(d_in[11], GAb, 256, flags + 1);
    cvt_small<<<1, 256, 0, stream>>>(d_in[12], EG,  256, flags + 1);
    cvt_small<<<1, 256, 0, stream>>>(d_in[13], EGb, 256, flags + 1);
    rowsum_kv<<<512, 256, 0, stream>>>(kv, kvsum, fM);

    const float scale = 1.0f / 128.0f;  // N^{-0.5} (cancels through inorm, kept for safety)
    dim3 gnn(N_DIM / 128, 2);

    // ---- UPPER branch: self-attention, batches 4..7 ----
    for (int b = 0; b < 4; ++b) {
        long fo = (long)(4 + b) * CN;
        gemm_nn_mfma<false, true, bf16><<<gnn, 256, 0, stream>>>(
            W_in, fM, feats, fM, fo, nullptr, nullptr, EMB, 256);
        row_stats<<<256, 256, 0, stream>>>(EMB, GA, GAb, ST1);
        gemm_nt_mfma<<<dim3(2, 2, 32), 256, 0, stream>>>(EMB, f1, EMB, f1, PART, 256);
        red_nt<<<256, 256, 0, stream>>>(PART, Gemb, 65536, 32);
        build_G<<<256, 256, 0, stream>>>(Gemb, ST1, Gf);
        gemm_small<false><<<dim3(4, 4), 256, 0, stream>>>(Wq_sa, fM, 256, Gf, f0, 256, T1, 256, 1.0f);
        gemm_small<true><<<dim3(4, 4), 256, 0, stream>>>(T1, f0, 256, Wk_sa, fM, 256, SC, 256, scale);
        inorm_softmax<<<256, 256, 0, stream>>>(SC, 256);
        gemm_small<false><<<dim3(4, 4), 256, 0, stream>>>(Wo_sa, fM, 256, SC, f0, 256, T2, 256, 1.0f);
        gemm_small<false><<<dim3(4, 4), 256, 0, stream>>>(T2, f0, 256, Wv_sa, fM, 256, Mm, 256, 1.0f);
        build_Ms_u<<<256, 256, 0, stream>>>(Mm, ST1, Ms, uvec);
        gemm_nn_mfma<false, false, bf16><<<gnn, 256, 0, stream>>>(
            Ms, f0, EMB, f1, 0, uvec, nullptr, SU, 256);
        row_stats<<<256, 256, 0, stream>>>(SU, EG, EGb, ST2);
        build_W2_v<<<256, 256, 0, stream>>>(W_out, fM, ST2, W2, vvec);
        gemm_nn_mfma<false, true, float><<<gnn, 256, 0, stream>>>(
            W2, f0, SU, f1, 0, vvec, nullptr, OUT + fo, 256);
    }

    // ---- LOWER branch: cross-attention, batches 0..3 ----
    for (int b = 0; b < 4; ++b) {
        long fo = (long)b * CN;
        gemm_nn_mfma<false, true, bf16><<<gnn, 256, 0, stream>>>(
            W_in, fM, feats, fM, fo, nullptr, nullptr, EMB, 256);
        row_stats<<<256, 256, 0, stream>>>(EMB, GA, GAb, ST1);
        gemm_nt_mfma<<<dim3(4, 2, 16), 256, 0, stream>>>(EMB, f1, kv, fM, PART, 512);
        red_nt<<<512, 256, 0, stream>>>(PART, Pemb, 131072, 16);
        build_P<<<256, 256, 0, stream>>>(Pemb, ST1, kvsum, Pm);
        gemm_small<false><<<dim3(8, 4), 256, 0, stream>>>(Wq_ca, fM, 256, Pm, f0, 512, SC, 512, scale);
        inorm_softmax<<<256, 256, 0, stream>>>(SC, 512);
        gemm_small<false><<<dim3(8, 4), 256, 0, stream>>>(Wo_ca, fM, 256, SC, f0, 512, M2, 512, 1.0f);
        gemm_nn_mfma<true, false, bf16><<<gnn, 256, 0, stream>>>(
            M2, f0, kv, fM, 0, nullptr, EMB, SU, 512);
        row_stats<<<256, 256, 0, stream>>>(SU, EG, EGb, ST2);
        build_W2_v<<<256, 256, 0, stream>>>(W_out, fM, ST2, W2, vvec);
        gemm_nn_mfma<false, true, float><<<gnn, 256, 0, stream>>>(
            W2, f0, SU, f1, 0, vvec, nullptr, OUT + fo, 256);
    }
}

// Round 2
// 1458.404 us; speedup vs baseline: 5.3097x; 2.0890x over previous
//
#include <hip/hip_runtime.h>
#include <hip/hip_bf16.h>

#define N_DIM 16384
#define CN (256L * 16384)
#define NT_Q 8          // split-K chunks for NT GEMMs
#define NT_KCH (N_DIM / NT_Q)

using bf16 = __hip_bfloat16;

typedef __attribute__((ext_vector_type(8))) short short8;
typedef __attribute__((ext_vector_type(4))) float f32x4;
typedef __attribute__((ext_vector_type(4))) unsigned int u32x4;

// ---------- small helpers ----------

__device__ __forceinline__ unsigned short f2bf(float x) {   // RNE float->bf16 (finite inputs)
    unsigned int u = __float_as_uint(x);
    u = (u + 0x7FFFu + ((u >> 16) & 1u)) >> 16;
    return (unsigned short)u;
}
__device__ __forceinline__ float bfus2f(unsigned short h) {
    return __uint_as_float(((unsigned int)h) << 16);
}

// MFMA via inline asm (gfx950 unified VGPR/AGPR file; D==C accumulate)
__device__ __forceinline__ void mfma16(f32x4& d, short8 a, short8 b) {
    asm("v_mfma_f32_16x16x32_bf16 %0, %1, %2, %0" : "+v"(d) : "v"(a), "v"(b));
}

// runtime-dtype load: isbf ? bf16 : fp32
__device__ inline float ldmix(const void* p, long i, int isbf) {
    return isbf ? __bfloat162float(((const bf16*)p)[i])
                : ((const float*)p)[i];
}

__device__ inline void st_out(float* p, long i, float v)  { p[i] = v; }
__device__ inline void st_out(bf16* p, long i, float v)   { p[i] = __float2bfloat16(v); }

__device__ inline float gelu_f(float x) {
    return 0.5f * x * (1.0f + erff(x * 0.70710678118654752440f));
}

__device__ inline float block_reduce_sum(float v, float* sh) {
    int t = threadIdx.x;
    sh[t] = v; __syncthreads();
    for (int s = 128; s >= 1; s >>= 1) {
        if (t < s) sh[t] += sh[t + s];
        __syncthreads();
    }
    float r = sh[0]; __syncthreads();
    return r;
}

__device__ inline float block_reduce_max(float v, float* sh) {
    int t = threadIdx.x;
    sh[t] = v; __syncthreads();
    for (int s = 128; s >= 1; s >>= 1) {
        if (t < s) sh[t] = fmaxf(sh[t], sh[t + s]);
        __syncthreads();
    }
    float r = sh[0]; __syncthreads();
    return r;
}

// write 16 bf16 elements to LDS from 2 (bf16 src) or 4 (fp32 src) u32x4 regs
__device__ __forceinline__ void wr16(short* d, const u32x4* r, int isbf) {
    if (isbf) {
        *(u32x4*)d = r[0]; *(u32x4*)(d + 8) = r[1];
    } else {
        #pragma unroll
        for (int g = 0; g < 2; ++g) {
            short8 h;
            #pragma unroll
            for (int i = 0; i < 8; ++i)
                h[i] = (short)f2bf(__uint_as_float(r[2*g + (i >> 2)][i & 3]));
            *(short8*)(d + g * 8) = h;
        }
    }
}

// ---------- dtype detection ----------

__global__ void detect_main(const unsigned short* __restrict__ p, int* __restrict__ flag) {
    __shared__ int cnt;
    int t = threadIdx.x;
    if (t == 0) cnt = 0;
    __syncthreads();
    int e = (p[t] >> 7) & 0xFF;
    if (e >= 90 && e <= 145) atomicAdd(&cnt, 1);
    __syncthreads();
    if (t == 0) *flag = (cnt >= 200) ? 1 : 0;
}

__global__ void detect_const(const unsigned short* __restrict__ p, int* __restrict__ flag) {
    __shared__ int zc;
    int t = threadIdx.x;
    if (t == 0) zc = 0;
    __syncthreads();
    if (p[t] == 0) atomicAdd(&zc, 1);
    __syncthreads();
    if (t == 0) *flag = (zc >= 64) ? 0 : 1;
}

__global__ void init_consts(int* flags) {
    flags[2] = 0;  // fp32 constant flag
    flags[3] = 1;  // bf16 constant flag
}

__global__ void cvt_small(const void* __restrict__ in, float* __restrict__ out,
                          int n, const int* __restrict__ flag) {
    int i = threadIdx.x;
    if (i < n) out[i] = ldmix(in, i, *flag);
}

// kvsum[j] = sum_n kv[j,n];  grid.x = 512  (vectorized loads)
__global__ void rowsum_kv(const void* __restrict__ kv, float* __restrict__ kvsum,
                          const int* __restrict__ flag) {
    __shared__ float sh[256];
    int j = blockIdx.x, t = threadIdx.x, isbf = *flag;
    float s = 0.f;
    if (isbf) {
        const short8* p = (const short8*)((const bf16*)kv + (long)j * N_DIM);
        for (int i = t; i < N_DIM / 8; i += 256) {
            short8 v = p[i];
            #pragma unroll
            for (int e = 0; e < 8; ++e) s += bfus2f((unsigned short)v[e]);
        }
    } else {
        const float4* p = (const float4*)((const float*)kv + (long)j * N_DIM);
        for (int i = t; i < N_DIM / 4; i += 256) {
            float4 v = p[i];
            s += v.x + v.y + v.z + v.w;
        }
    }
    s = block_reduce_sum(s, sh);
    if (t == 0) kvsum[j] = s;
}

// per-row stats of bf16 Z[NB][256][N_DIM]: st[z*256+row]=(s, t, mean, 0); grid (256, NB)
__global__ void row_stats(const bf16* __restrict__ Z,
                          const float* __restrict__ gamma,
                          const float* __restrict__ beta,
                          float4* __restrict__ st) {
    __shared__ float sh[256];
    int row = blockIdx.x, z = blockIdx.y, t = threadIdx.x;
    const short8* zp = (const short8*)(Z + (long)z * CN + (long)row * N_DIM);
    float s = 0.f, s2 = 0.f;
    for (int i = t; i < N_DIM / 8; i += 256) {
        short8 v = zp[i];
        #pragma unroll
        for (int e = 0; e < 8; ++e) {
            float x = bfus2f((unsigned short)v[e]);
            s += x; s2 += x * x;
        }
    }
    float sum  = block_reduce_sum(s, sh);
    float sum2 = block_reduce_sum(s2, sh);
    if (t == 0) {
        float mean = sum * (1.0f / N_DIM);
        float var  = fmaxf(sum2 * (1.0f / N_DIM) - mean * mean, 0.0f);
        float inv  = rsqrtf(var + 1e-5f);
        float sc = gamma[row] * inv;
        st[z * 256 + row] = make_float4(sc, beta[row] - mean * sc, mean, 0.0f);
    }
}

// in-place instance-norm + softmax over rows of length L (256 or 512); grid.x = nrows
__global__ void inorm_softmax(float* __restrict__ S, int L) {
    __shared__ float sh[256];
    float* row = S + (long)blockIdx.x * L;
    int t = threadIdx.x;
    float x0 = row[t];
    float x1 = (L > 256) ? row[t + 256] : 0.0f;
    float sum = block_reduce_sum(x0 + x1, sh);
    float mean = sum / (float)L;
    float d0 = x0 - mean;
    float d1 = (L > 256) ? (x1 - mean) : 0.0f;
    float var = fmaxf(block_reduce_sum(d0 * d0 + d1 * d1, sh) / (float)L, 0.0f);
    float inv = rsqrtf(var + 1e-5f);
    float y0 = d0 * inv, y1 = d1 * inv;
    float mx = (L > 256) ? fmaxf(y0, y1) : y0;
    float gmax = block_reduce_max(mx, sh);
    float e0 = expf(y0 - gmax);
    float e1 = (L > 256) ? expf(y1 - gmax) : 0.0f;
    float es = block_reduce_sum(e0 + e1, sh);
    float rinv = 1.0f / es;
    row[t] = e0 * rinv;
    if (L > 256) row[t + 256] = e1 * rinv;
}

// ---------------------------------------------------------------------------
// MFMA big NN GEMM, z-batched:
//   Cout[z][256][N_DIM] = A(z)[256][K] @ B(z)[K][N_DIM] (+rowc)(+Dres)(gelu)
// A split hi/lo bf16 (fp32-accurate); B single bf16.
// tile 128x128, BK=32, 4 waves (2x2), double-buffered LDS.
// grid (N_DIM/128, 2, NB), block 256. LDS 57.6KB -> 2 blocks/CU.
// ---------------------------------------------------------------------------
template <bool RES, bool GELU, typename TOUT>
__global__ __launch_bounds__(256) void gemm_nn_mfma(
    const void* __restrict__ Ag, const int* __restrict__ fA, long astr,
    const void* __restrict__ Bg, const int* __restrict__ fB, long bbase, long bstr,
    const float* __restrict__ rowc, int rstr,
    const bf16* __restrict__ Dres, long dstr,
    TOUT* __restrict__ Cout, long cstr, int K)
{
    __shared__ short Ahi[2][128 * 40];   // [row][k] pitch 40
    __shared__ short Alo[2][128 * 40];
    __shared__ short Bsm[2][32 * 130];   // [k][n] pitch 130 -> conflict-free frag gather

    int t = threadIdx.x;
    int af = *fA, bfg = *fB;
    int z = blockIdx.z;
    int n0 = blockIdx.x * 128, m0 = blockIdx.y * 128;
    int wave = t >> 6, lane = t & 63;
    int wr = wave >> 1, wc = wave & 1;
    int l15 = lane & 15, lkg = lane >> 4;
    int arow = t & 127, ah2 = t >> 7;

    long abase = (long)z * astr;
    long bz = bbase + (long)z * bstr;

    u32x4 ra[4], rb[4];
    f32x4 acc[4][4];
    f32x4 zz = {0.f, 0.f, 0.f, 0.f};
    #pragma unroll
    for (int mi = 0; mi < 4; ++mi)
        #pragma unroll
        for (int ni = 0; ni < 4; ++ni) acc[mi][ni] = zz;

    auto STAGE_LOAD = [&](int k0) {
        long ga = abase + (long)(m0 + arow) * K + k0 + ah2 * 16;
        if (af) {
            const u32x4* p = (const u32x4*)((const unsigned short*)Ag + ga);
            ra[0] = p[0]; ra[1] = p[1];
        } else {
            const u32x4* p = (const u32x4*)((const float*)Ag + ga);
            ra[0] = p[0]; ra[1] = p[1]; ra[2] = p[2]; ra[3] = p[3];
        }
        #pragma unroll
        for (int c = 0; c < 2; ++c) {
            int q = c * 256 + t;
            int k = q >> 4, n = (q & 15) * 8;
            long gb = bz + (long)(k0 + k) * N_DIM + n0 + n;
            if (bfg) {
                rb[c * 2] = *(const u32x4*)((const unsigned short*)Bg + gb);
            } else {
                const u32x4* p = (const u32x4*)((const float*)Bg + gb);
                rb[c * 2] = p[0]; rb[c * 2 + 1] = p[1];
            }
        }
    };

    auto STAGE_WRITE = [&](int b2) {
        short* dh = &Ahi[b2][arow * 40 + ah2 * 16];
        short* dl = &Alo[b2][arow * 40 + ah2 * 16];
        if (af) {
            *(u32x4*)dh = ra[0]; *(u32x4*)(dh + 8) = ra[1];
            u32x4 z4 = {0u, 0u, 0u, 0u};
            *(u32x4*)dl = z4; *(u32x4*)(dl + 8) = z4;
        } else {
            #pragma unroll
            for (int g = 0; g < 2; ++g) {
                short8 h, l;
                #pragma unroll
                for (int i = 0; i < 8; ++i) {
                    float x = __uint_as_float(ra[2 * g + (i >> 2)][i & 3]);
                    unsigned short hu = f2bf(x);
                    h[i] = (short)hu;
                    l[i] = (short)f2bf(x - bfus2f(hu));
                }
                *(short8*)(dh + g * 8) = h;
                *(short8*)(dl + g * 8) = l;
            }
        }
        #pragma unroll
        for (int c = 0; c < 2; ++c) {
            int q = c * 256 + t;
            int k = q >> 4, n = (q & 15) * 8;
            unsigned int* wp = (unsigned int*)&Bsm[b2][k * 130 + n];
            if (bfg) {
                const unsigned int* s = (const unsigned int*)&rb[c * 2];
                wp[0] = s[0]; wp[1] = s[1]; wp[2] = s[2]; wp[3] = s[3];
            } else {
                #pragma unroll
                for (int j = 0; j < 4; ++j) {
                    float x0 = __uint_as_float(rb[c * 2 + (j >> 1)][(j & 1) * 2]);
                    float x1 = __uint_as_float(rb[c * 2 + (j >> 1)][(j & 1) * 2 + 1]);
                    wp[j] = (unsigned int)f2bf(x0) | ((unsigned int)f2bf(x1) << 16);
                }
            }
        }
    };

    auto COMPUTE = [&](int b2) {
        const short* AhB = &Ahi[b2][0];
        const short* AlB = &Alo[b2][0];
        const short* BsB = &Bsm[b2][0];
        short8 bfr[4];
        #pragma unroll
        for (int ni = 0; ni < 4; ++ni) {
            short8 v;
            #pragma unroll
            for (int e = 0; e < 8; ++e)
                v[e] = BsB[(lkg * 8 + e) * 130 + wc * 64 + ni * 16 + l15];
            bfr[ni] = v;
        }
        short8 ahf[4], alf[4];
        #pragma unroll
        for (int mi = 0; mi < 4; ++mi) {
            int ro = (wr * 64 + mi * 16 + l15) * 40 + lkg * 8;
            ahf[mi] = *(const short8*)(AhB + ro);
            alf[mi] = *(const short8*)(AlB + ro);
        }
        #pragma unroll
        for (int mi = 0; mi < 4; ++mi)
            #pragma unroll
            for (int ni = 0; ni < 4; ++ni)
                mfma16(acc[mi][ni], ahf[mi], bfr[ni]);
        #pragma unroll
        for (int mi = 0; mi < 4; ++mi)
            #pragma unroll
            for (int ni = 0; ni < 4; ++ni)
                mfma16(acc[mi][ni], alf[mi], bfr[ni]);
    };

    int nsteps = K >> 5;
    STAGE_LOAD(0);
    STAGE_WRITE(0);
    __syncthreads();
    int buf = 0;
    for (int s = 0; s < nsteps; ++s) {
        bool pre = (s + 1 < nsteps);
        if (pre) STAGE_LOAD((s + 1) << 5);
        COMPUTE(buf);
        if (pre) STAGE_WRITE(buf ^ 1);
        __syncthreads();
        buf ^= 1;
    }

    long cz = (long)z * cstr;
    long dz = (long)z * dstr;
    #pragma unroll
    for (int mi = 0; mi < 4; ++mi) {
        #pragma unroll
        for (int ni = 0; ni < 4; ++ni) {
            int mbase = m0 + wr * 64 + mi * 16 + lkg * 4;
            int n = n0 + wc * 64 + ni * 16 + l15;
            #pragma unroll
            for (int r = 0; r < 4; ++r) {
                int m = mbase + r;
                float v = acc[mi][ni][r];
                if (rowc) v += rowc[z * rstr + m];
                if (RES)  v += __bfloat162float(Dres[dz + (long)m * N_DIM + n]);
                if (GELU) v = gelu_f(v);
                st_out(Cout, cz + (long)m * N_DIM + n, v);
            }
        }
    }
}

// ---------------------------------------------------------------------------
// MFMA big NT GEMM, z-batched split-K:
//   Pout[zb*NT_Q+q][256][J] = A(zb)[256][kchunk] @ B(zb)[J][kchunk]^T
// grid (J/128, 2, NB*NT_Q), block 256.
// ---------------------------------------------------------------------------
__global__ __launch_bounds__(256) void gemm_nt_mfma(
    const void* __restrict__ Ag, const int* __restrict__ fA, long astr,
    const void* __restrict__ Bg, const int* __restrict__ fB, long bstr,
    float* __restrict__ Pout, int J)
{
    __shared__ short Ash[2][128 * 40];
    __shared__ short Bs2[2][128 * 40];

    int t = threadIdx.x;
    int af = *fA, bfg = *fB;
    int zq = blockIdx.z;
    int zb = zq >> 3, q = zq & 7;           // NT_Q = 8
    int j0 = blockIdx.x * 128, m0 = blockIdx.y * 128;
    int kz = q * NT_KCH;
    int wave = t >> 6, lane = t & 63;
    int wr = wave >> 1, wc = wave & 1;
    int l15 = lane & 15, lkg = lane >> 4;
    int arow = t & 127, ah2 = t >> 7;

    long abase = (long)zb * astr;
    long bbase = (long)zb * bstr;

    u32x4 ra[4], rbn[4];
    f32x4 acc[4][4];
    f32x4 zz = {0.f, 0.f, 0.f, 0.f};
    #pragma unroll
    for (int mi = 0; mi < 4; ++mi)
        #pragma unroll
        for (int nj = 0; nj < 4; ++nj) acc[mi][nj] = zz;

    auto STAGE_LOAD = [&](int k0) {
        long ga = abase + (long)(m0 + arow) * N_DIM + k0 + ah2 * 16;
        if (af) {
            const u32x4* p = (const u32x4*)((const unsigned short*)Ag + ga);
            ra[0] = p[0]; ra[1] = p[1];
        } else {
            const u32x4* p = (const u32x4*)((const float*)Ag + ga);
            ra[0] = p[0]; ra[1] = p[1]; ra[2] = p[2]; ra[3] = p[3];
        }
        long gb = bbase + (long)(j0 + arow) * N_DIM + k0 + ah2 * 16;
        if (bfg) {
            const u32x4* p = (const u32x4*)((const unsigned short*)Bg + gb);
            rbn[0] = p[0]; rbn[1] = p[1];
        } else {
            const u32x4* p = (const u32x4*)((const float*)Bg + gb);
            rbn[0] = p[0]; rbn[1] = p[1]; rbn[2] = p[2]; rbn[3] = p[3];
        }
    };

    auto STAGE_WRITE = [&](int b2) {
        wr16(&Ash[b2][arow * 40 + ah2 * 16], ra, af);
        wr16(&Bs2[b2][arow * 40 + ah2 * 16], rbn, bfg);
    };

    auto COMPUTE = [&](int b2) {
        const short* AsB = &Ash[b2][0];
        const short* BsB = &Bs2[b2][0];
        short8 a[4], b[4];
        #pragma unroll
        for (int mi = 0; mi < 4; ++mi)
            a[mi] = *(const short8*)(AsB + (wr * 64 + mi * 16 + l15) * 40 + lkg * 8);
        #pragma unroll
        for (int nj = 0; nj < 4; ++nj)
            b[nj] = *(const short8*)(BsB + (wc * 64 + nj * 16 + l15) * 40 + lkg * 8);
        #pragma unroll
        for (int mi = 0; mi < 4; ++mi)
            #pragma unroll
            for (int nj = 0; nj < 4; ++nj)
                mfma16(acc[mi][nj], a[mi], b[nj]);
    };

    int nsteps = NT_KCH >> 5;
    STAGE_LOAD(kz);
    STAGE_WRITE(0);
    __syncthreads();
    int buf = 0;
    for (int s = 0; s < nsteps; ++s) {
        bool pre = (s + 1 < nsteps);
        if (pre) STAGE_LOAD(kz + ((s + 1) << 5));
        COMPUTE(buf);
        if (pre) STAGE_WRITE(buf ^ 1);
        __syncthreads();
        buf ^= 1;
    }

    float* P = Pout + (long)zq * 256 * J;
    #pragma unroll
    for (int mi = 0; mi < 4; ++mi) {
        #pragma unroll
        for (int nj = 0; nj < 4; ++nj) {
            int mbase = m0 + wr * 64 + mi * 16 + lkg * 4;
            int j = j0 + wc * 64 + nj * 16 + l15;
            #pragma unroll
            for (int r = 0; r < 4; ++r)
                P[(long)(mbase + r) * J + j] = acc[mi][nj][r];
        }
    }
}

// ---------------------------------------------------------------------------
// Small fp32 GEMM, z-batched: C(z)[256][Nn] = alpha * A(z)[256][K] @ op(B(z))
// ---------------------------------------------------------------------------
template <bool TRANSB>
__global__ __launch_bounds__(256) void gemm_small(
    const void* __restrict__ A, const int* __restrict__ fA, int K, long astr,
    const void* __restrict__ B, const int* __restrict__ fB, int ldb, long bstr,
    float* __restrict__ C, int Nn, long cstr, float alpha)
{
    __shared__ float As[64][65];
    __shared__ float Bs[64][65];
    int af = *fA, bfg = *fB;
    int z = blockIdx.z;
    int j0 = blockIdx.x * 64, m0 = blockIdx.y * 64;
    int t = threadIdx.x, tx = t & 15, ty = t >> 4;
    long ab = (long)z * astr, bb = (long)z * bstr;
    float acc[4][4] = {{0.f}};

    for (int k0 = 0; k0 < K; k0 += 64) {
        #pragma unroll
        for (int i = 0; i < 16; ++i) {
            int idx = t + i * 256;
            int r = idx >> 6, c = idx & 63;
            As[c][r] = ldmix(A, ab + (long)(m0 + r) * K + (k0 + c), af);
            if (TRANSB)
                Bs[c][r] = ldmix(B, bb + (long)(j0 + r) * ldb + (k0 + c), bfg);
            else
                Bs[r][c] = ldmix(B, bb + (long)(k0 + r) * ldb + (j0 + c), bfg);
        }
        __syncthreads();
        #pragma unroll
        for (int kk = 0; kk < 64; ++kk) {
            float a[4], bbv[4];
            #pragma unroll
            for (int i = 0; i < 4; ++i) a[i] = As[kk][ty * 4 + i];
            #pragma unroll
            for (int j = 0; j < 4; ++j) bbv[j] = Bs[kk][tx * 4 + j];
            #pragma unroll
            for (int i = 0; i < 4; ++i)
                #pragma unroll
                for (int j = 0; j < 4; ++j)
                    acc[i][j] = fmaf(a[i], bbv[j], acc[i][j]);
        }
        __syncthreads();
    }

    #pragma unroll
    for (int i = 0; i < 4; ++i) {
        int m = m0 + ty * 4 + i;
        #pragma unroll
        for (int j = 0; j < 4; ++j)
            C[(long)z * cstr + (long)m * Nn + (j0 + tx * 4 + j)] = acc[i][j] * alpha;
    }
}

// ---------- affine-stat fold kernels (z-batched; split-K sum fused in) ----------

// Gram: G(z) = E E^T from PART sum + affine stats; grid (256, NB)
__global__ void build_G(const float* __restrict__ PART, const float4* __restrict__ st,
                        float* __restrict__ G) {
    int z = blockIdx.y, c = blockIdx.x, d = threadIdx.x;
    float g = 0.f;
    for (int q = 0; q < NT_Q; ++q)
        g += PART[((long)(z * NT_Q + q)) * 65536 + c * 256 + d];
    float4 a = st[z * 256 + c], b = st[z * 256 + d];
    float rc = a.z * (float)N_DIM, rd = b.z * (float)N_DIM;
    G[(long)z * 65536 + c * 256 + d] = a.x * b.x * g
                   + a.x * b.y * rc + a.y * b.x * rd
                   + (float)N_DIM * a.y * b.y;
}

// P(z)[c,j] = s_c*Pemb[c,j] + t_c*kvsum[j]  (Pemb = split-K sum); grid (256, NB)
__global__ void build_P(const float* __restrict__ PART, const float4* __restrict__ st,
                        const float* __restrict__ kvsum, float* __restrict__ P) {
    int z = blockIdx.y, c = blockIdx.x, t = threadIdx.x;
    float4 a = st[z * 256 + c];
    for (int j = t; j < 512; j += 256) {
        float s = 0.f;
        for (int q = 0; q < NT_Q; ++q)
            s += PART[((long)(z * NT_Q + q)) * 131072 + c * 512 + j];
        P[(long)z * 131072 + c * 512 + j] = a.x * s + a.y * kvsum[j];
    }
}

// Ms(z) = M(z)*diag(s) + I ; u(z)[m] = sum_c M[m,c]*t_c; grid (256, NB)
__global__ void build_Ms_u(const float* __restrict__ M, const float4* __restrict__ st,
                           float* __restrict__ Ms, float* __restrict__ u) {
    __shared__ float sh[256];
    int z = blockIdx.y, m = blockIdx.x, c = threadIdx.x;
    float mv = M[(long)z * 65536 + m * 256 + c];
    float4 b = st[z * 256 + c];
    Ms[(long)z * 65536 + m * 256 + c] = mv * b.x + ((m == c) ? 1.0f : 0.0f);
    float uu = block_reduce_sum(mv * b.y, sh);
    if (c == 0) u[z * 256 + m] = uu;
}

// W2(z) = W_out*diag(s2(z)) ; v(z)[o] = sum_c W_out[o,c]*t2_c; grid (256, NB)
__global__ void build_W2_v(const void* __restrict__ Wout, const int* __restrict__ fM,
                           const float4* __restrict__ st,
                           float* __restrict__ W2, float* __restrict__ v) {
    __shared__ float sh[256];
    int z = blockIdx.y, o = blockIdx.x, c = threadIdx.x;
    float wv = ldmix(Wout, (long)o * 256 + c, *fM);
    float4 b = st[z * 256 + c];
    W2[(long)z * 65536 + o * 256 + c] = wv * b.x;
    float vv = block_reduce_sum(wv * b.y, sh);
    if (c == 0) v[z * 256 + o] = vv;
}

extern "C" void kernel_launch(void* const* d_in, const int* in_sizes, int n_in,
                              void* d_out, int out_size, void* d_ws, size_t ws_size,
                              hipStream_t stream) {
    const void* feats = d_in[0];
    const void* kv    = d_in[1];
    const void* W_in  = d_in[2];
    const void* W_out = d_in[3];
    const void* Wq_sa = d_in[4];
    const void* Wk_sa = d_in[5];
    const void* Wv_sa = d_in[6];
    const void* Wo_sa = d_in[7];
    const void* Wq_ca = d_in[8];
    const void* Wo_ca = d_in[9];
    float* OUT = (float*)d_out;   // reference output dtype is float32

    // ---- workspace (~160 MB; ws is 512 MB per harness fill evidence) ----
    char* w = (char*)d_ws;
    auto alloc = [&](size_t bytes) { char* p = w; w += (bytes + 255) & ~255UL; return p; };
    int*    flags = (int*)alloc(64);
    float*  GA    = (float*)alloc(1024);
    float*  GAb   = (float*)alloc(1024);
    float*  EG    = (float*)alloc(1024);
    float*  EGb   = (float*)alloc(1024);
    float*  kvsum = (float*)alloc(2048);
    float4* ST1   = (float4*)alloc(8 * 256 * 16);     // per-batch inorm stats (emb)
    float4* ST2   = (float4*)alloc(8 * 256 * 16);     // per-batch inorm stats (enc)
    float*  Gf4   = (float*)alloc(4L * 65536 * 4);
    float*  T1_4  = (float*)alloc(4L * 65536 * 4);
    float*  T2_4  = (float*)alloc(4L * 65536 * 4);
    float*  Mm4   = (float*)alloc(4L * 65536 * 4);
    float*  Ms4   = (float*)alloc(4L * 65536 * 4);
    float*  W2_8  = (float*)alloc(8L * 65536 * 4);
    float*  SC4   = (float*)alloc(4L * 65536 * 4);    // upper scores (256 wide)
    float*  SCL4  = (float*)alloc(4L * 131072 * 4);   // lower scores (512 wide)
    float*  Pm4   = (float*)alloc(4L * 131072 * 4);
    float*  M2_4  = (float*)alloc(4L * 131072 * 4);
    float*  uvec  = (float*)alloc(4 * 256 * 4);
    float*  vvec  = (float*)alloc(8 * 256 * 4);
    float*  PART  = (float*)alloc(32L * 131072 * 4);  // 16 MB: NT split-K partials
    bf16*   EMB8  = (bf16*)alloc(8 * CN * 2);         // 64 MB
    bf16*   SU8   = (bf16*)alloc(8 * CN * 2);         // 64 MB

    const int* fM = flags + 0;  // detected dtype of main tensors
    const int* f0 = flags + 2;  // fp32 constant
    const int* f1 = flags + 3;  // bf16 constant
    const float scale = 1.0f / 128.0f;  // N^{-0.5}

    // ---- setup ----
    detect_main<<<1, 256, 0, stream>>>((const unsigned short*)feats, flags + 0);
    detect_const<<<1, 256, 0, stream>>>((const unsigned short*)d_in[10], flags + 1);
    init_consts<<<1, 1, 0, stream>>>(flags);
    cvt_small<<<1, 256, 0, stream>>>(d_in[10], GA,  256, flags + 1);
    cvt_small<<<1, 256, 0, stream>>>(d_in[11], GAb, 256, flags + 1);
    cvt_small<<<1, 256, 0, stream>>>(d_in[12], EG,  256, flags + 1);
    cvt_small<<<1, 256, 0, stream>>>(d_in[13], EGb, 256, flags + 1);
    rowsum_kv<<<512, 256, 0, stream>>>(kv, kvsum, fM);

    // ---- phase 1: EMB for all 8 batches, one dispatch ----
    gemm_nn_mfma<false, true, bf16><<<dim3(128, 2, 8), 256, 0, stream>>>(
        W_in, fM, 0, feats, fM, 0, CN, nullptr, 0, nullptr, 0, EMB8, CN, 256);
    row_stats<<<dim3(256, 8), 256, 0, stream>>>(EMB8, GA, GAb, ST1);

    // ---- phase 2a: UPPER branch (batches 4..7), z-batched ----
    gemm_nt_mfma<<<dim3(2, 2, 32), 256, 0, stream>>>(
        EMB8 + 4 * CN, f1, CN, EMB8 + 4 * CN, f1, CN, PART, 256);
    build_G<<<dim3(256, 4), 256, 0, stream>>>(PART, ST1 + 4 * 256, Gf4);
    gemm_small<false><<<dim3(4, 4, 4), 256, 0, stream>>>(
        Wq_sa, fM, 256, 0, Gf4, f0, 256, 65536, T1_4, 256, 65536, 1.0f);
    gemm_small<true><<<dim3(4, 4, 4), 256, 0, stream>>>(
        T1_4, f0, 256, 65536, Wk_sa, fM, 256, 0, SC4, 256, 65536, scale);
    inorm_softmax<<<1024, 256, 0, stream>>>(SC4, 256);
    gemm_small<false><<<dim3(4, 4, 4), 256, 0, stream>>>(
        Wo_sa, fM, 256, 0, SC4, f0, 256, 65536, T2_4, 256, 65536, 1.0f);
    gemm_small<false><<<dim3(4, 4, 4), 256, 0, stream>>>(
        T2_4, f0, 256, 65536, Wv_sa, fM, 256, 0, Mm4, 256, 65536, 1.0f);
    build_Ms_u<<<dim3(256, 4), 256, 0, stream>>>(Mm4, ST1 + 4 * 256, Ms4, uvec);
    gemm_nn_mfma<false, false, bf16><<<dim3(128, 2, 4), 256, 0, stream>>>(
        Ms4, f0, 65536, EMB8, f1, 4 * CN, CN, uvec, 256, nullptr, 0, SU8 + 4 * CN, CN, 256);

    // ---- phase 2b: LOWER branch (batches 0..3), z-batched ----
    gemm_nt_mfma<<<dim3(4, 2, 32), 256, 0, stream>>>(
        EMB8, f1, CN, kv, fM, 0, PART, 512);
    build_P<<<dim3(256, 4), 256, 0, stream>>>(PART, ST1, kvsum, Pm4);
    gemm_small<false><<<dim3(8, 4, 4), 256, 0, stream>>>(
        Wq_ca, fM, 256, 0, Pm4, f0, 512, 131072, SCL4, 512, 131072, scale);
    inorm_softmax<<<1024, 256, 0, stream>>>(SCL4, 512);
    gemm_small<false><<<dim3(8, 4, 4), 256, 0, stream>>>(
        Wo_ca, fM, 256, 0, SCL4, f0, 512, 131072, M2_4, 512, 131072, 1.0f);
    gemm_nn_mfma<true, false, bf16><<<dim3(128, 2, 4), 256, 0, stream>>>(
        M2_4, f0, 131072, kv, fM, 0, 0, nullptr, 0, EMB8, CN, SU8, CN, 512);

    // ---- phase 3: encoder norm + output GEMM for all 8 batches ----
    row_stats<<<dim3(256, 8), 256, 0, stream>>>(SU8, EG, EGb, ST2);
    build_W2_v<<<dim3(256, 8), 256, 0, stream>>>(W_out, fM, ST2, W2_8, vvec);
    gemm_nn_mfma<false, true, float><<<dim3(128, 2, 8), 256, 0, stream>>>(
        W2_8, f0, 65536, SU8, f1, 0, CN, vvec, 256, nullptr, 0, OUT, CN, 256);
}